// Round 3
// baseline (737.551 us; speedup 1.0000x reference)
//
#include <hip/hip_runtime.h>
#include <hip/hip_bf16.h>

// dims
#define B_ 8
#define S_ 2048
#define D_ 1024
#define H1_ 512
#define DH_ 128
#define DV_ 512
#define DOUT_ 512

typedef __bf16 bf16x8 __attribute__((ext_vector_type(8)));
typedef __bf16 bf16x4 __attribute__((ext_vector_type(4)));
typedef float  f32x4  __attribute__((ext_vector_type(4)));

#define SM_SCALE 0.08838834764831845f  // 1/sqrt(128), folded into W12T

// ---------------------------------------------------------------------------
// prep 1: W12T[h][d] = scale * sum_j w1[d][j]*w2[j][h]; W46T likewise (no scale)
// ---------------------------------------------------------------------------
__global__ __launch_bounds__(256) void prep_w12(
    const float* __restrict__ w1, const float* __restrict__ w2,
    const float* __restrict__ w4, const float* __restrict__ w6,
    __bf16* __restrict__ w12t, __bf16* __restrict__ w46t) {
  int tid = blockIdx.x * 256 + threadIdx.x;   // 131072 threads
  const float* wa; const float* wb; __bf16* o; float sc;
  if (blockIdx.y == 0) { wa = w1; wb = w2; o = w12t; sc = SM_SCALE; }
  else                 { wa = w4; wb = w6; o = w46t; sc = 1.0f; }
  int h = tid & 127;        // 0..127
  int d = tid >> 7;         // 0..1023
  float acc = 0.f;
  for (int j = 0; j < H1_; ++j)
    acc += wa[d * H1_ + j] * wb[j * DH_ + h];
  o[h * D_ + d] = (__bf16)(acc * sc);   // transposed store
}

// ---------------------------------------------------------------------------
// prep 2: w3T[n][d] = w3[d][n];  W7sT[n][k] = w7[k][n] + w7[k+512][n]
// ---------------------------------------------------------------------------
__global__ __launch_bounds__(256) void prep_w3_w7(
    const float* __restrict__ w3, const float* __restrict__ w7,
    __bf16* __restrict__ w3t, __bf16* __restrict__ w7st) {
  int tid = blockIdx.x * 256 + threadIdx.x;   // 786432 threads
  if (tid < D_ * DV_) {
    int n = tid & 511, d = tid >> 9;
    w3t[n * D_ + d] = (__bf16)w3[d * DV_ + n];
  } else {
    int t = tid - D_ * DV_;
    int n = t & 511, kk = t >> 9;
    w7st[n * DV_ + kk] = (__bf16)(w7[kk * DOUT_ + n] + w7[(kk + DV_) * DOUT_ + n]);
  }
}

// ---------------------------------------------------------------------------
// prep 3: VT[b][n][t] = (bf16) v[b][t][n]   (32x32 LDS tile transpose)
// ---------------------------------------------------------------------------
__global__ __launch_bounds__(256) void prep_vt(
    const float* __restrict__ v, __bf16* __restrict__ vt) {
  __shared__ float tile[32][33];
  int b = blockIdx.z;
  int t0 = blockIdx.x * 32, n0 = blockIdx.y * 32;
  int tx = threadIdx.x & 31, ty = threadIdx.x >> 5;  // 32x8
  const float* vb = v + (size_t)b * S_ * DV_;
  for (int i = 0; i < 4; ++i)
    tile[ty + 8 * i][tx] = vb[(size_t)(t0 + ty + 8 * i) * DV_ + n0 + tx];
  __syncthreads();
  __bf16* vtb = vt + (size_t)b * DV_ * S_;
  for (int i = 0; i < 4; ++i)
    vtb[(size_t)(n0 + ty + 8 * i) * S_ + t0 + tx] = (__bf16)tile[tx][ty + 8 * i];
}

// ---------------------------------------------------------------------------
// bf16 MFMA GEMM: C = A @ B, BT given N x K.
// ---------------------------------------------------------------------------
template <typename AT, typename OT, bool FUSE>
__global__ __launch_bounds__(256) void gemm_mfma(
    const AT* __restrict__ A1, const AT* __restrict__ A2,
    const __bf16* __restrict__ BT, OT* __restrict__ C,
    const int M, const int N, const int K) {
  __shared__ __bf16 As[128 * 40];
  const int tid = threadIdx.x;
  const int mBase = blockIdx.x * 128;
  const int nBase = blockIdx.y * 128;
  const int wave = tid >> 6, lane = tid & 63;
  const int wr = wave >> 1, wc = wave & 1;
  const int l16 = lane & 15, quad = lane >> 4;

  f32x4 acc[4][4] = {};
  const int nb = nBase + wc * 64;

  bf16x8 bfr[4], bnx[4];
  for (int nt = 0; nt < 4; ++nt)
    bfr[nt] = *(const bf16x8*)(BT + (size_t)(nb + nt * 16 + l16) * K + quad * 8);

  for (int k0 = 0; k0 < K; k0 += 32) {
    for (int i = 0; i < 4; ++i) {
      int ch = tid + 256 * i;
      int row = ch >> 3, k4 = (ch & 7) << 2;
      size_t off = (size_t)(mBase + row) * K + k0 + k4;
      float f0, f1, f2, f3;
      if constexpr (sizeof(AT) == 4) {
        float4 vv = *(const float4*)((const float*)A1 + off);
        f0 = vv.x; f1 = vv.y; f2 = vv.z; f3 = vv.w;
        if constexpr (FUSE) {
          float4 v2 = *(const float4*)((const float*)A2 + off);
          f0 += v2.x; f1 += v2.y; f2 += v2.z; f3 += v2.w;
        }
      } else {
        bf16x4 vv = *(const bf16x4*)((const __bf16*)A1 + off);
        f0 = (float)vv[0]; f1 = (float)vv[1]; f2 = (float)vv[2]; f3 = (float)vv[3];
        if constexpr (FUSE) {
          bf16x4 v2 = *(const bf16x4*)((const __bf16*)A2 + off);
          f0 += (float)v2[0]; f1 += (float)v2[1]; f2 += (float)v2[2]; f3 += (float)v2[3];
        }
      }
      bf16x4 w; w[0] = (__bf16)f0; w[1] = (__bf16)f1; w[2] = (__bf16)f2; w[3] = (__bf16)f3;
      *(bf16x4*)&As[row * 40 + k4] = w;
    }
    __syncthreads();

    if (k0 + 32 < K)
      for (int nt = 0; nt < 4; ++nt)
        bnx[nt] = *(const bf16x8*)(BT + (size_t)(nb + nt * 16 + l16) * K + (k0 + 32) + quad * 8);

    bf16x8 afr[4];
    for (int mt = 0; mt < 4; ++mt)
      afr[mt] = *(bf16x8*)&As[(wr * 64 + mt * 16 + l16) * 40 + quad * 8];

    for (int mt = 0; mt < 4; ++mt)
      for (int nt = 0; nt < 4; ++nt)
        acc[mt][nt] = __builtin_amdgcn_mfma_f32_16x16x32_bf16(afr[mt], bfr[nt], acc[mt][nt], 0, 0, 0);
    __syncthreads();

    for (int nt = 0; nt < 4; ++nt) bfr[nt] = bnx[nt];
  }

  for (int mt = 0; mt < 4; ++mt) {
    int rowb = mBase + wr * 64 + mt * 16 + quad * 4;
    for (int nt = 0; nt < 4; ++nt) {
      int col = nBase + wc * 64 + nt * 16 + l16;
      for (int r = 0; r < 4; ++r)
        C[(size_t)(rowb + r) * N + col] = (OT)acc[mt][nt][r];
    }
  }
}

// ---------------------------------------------------------------------------
// MFMA flash attention. 256 thr = 4 autonomous waves (no __syncthreads).
// Each wave: same 16 query rows, its own 128-wide V-column chunk.
//   S^T = K3 @ Q2^T  (recomputed per wave: 8 MFMAs / 32 keys)
//   online softmax: alpha uniform per lane (col = qrow = l16)
//   P -> per-wave LDS -> B-frag;  out^T chunk = VT_chunk @ P (8 MFMAs)
// Grid: bx -> b = bx&7 (batch==XCD for L2 locality), tt = bx>>3 with
// small/large pairing so consecutive blocks have ~equal causal work.
// ---------------------------------------------------------------------------
__global__ __launch_bounds__(256, 4) void flash_attn_mfma(
    const __bf16* __restrict__ q2, const __bf16* __restrict__ k3,
    const __bf16* __restrict__ vt, __bf16* __restrict__ attn) {
  __shared__ __bf16 Pb[4][16 * 40];   // per-wave 16 rows x 80B stride
  const int tid = threadIdx.x;
  const int wave = tid >> 6, lane = tid & 63;
  const int l16 = lane & 15, quad = lane >> 4;
  const int bx = blockIdx.x;            // 0..1023
  const int b = bx & 7;                 // batch-major -> XCD-pinned working set
  const int tt = bx >> 3;               // 0..127
  const int tile = (tt & 1) ? (127 - (tt >> 1)) : (tt >> 1);  // pair small/large
  const int q0 = tile * 16;
  const int vc0 = wave * 128;           // this wave's V-column chunk

  const __bf16* q2b = q2 + ((size_t)b * S_ + q0) * DH_;
  const __bf16* k3b = k3 + (size_t)b * S_ * DH_;
  const __bf16* vtb = vt + ((size_t)b * DV_ + vc0) * S_;

  // Q B-frags: lane holds Q2[qrow=l16][dh=c*32+quad*8 ..+7]
  bf16x8 qf[4];
  for (int c = 0; c < 4; ++c)
    qf[c] = *(const bf16x8*)(q2b + l16 * DH_ + c * 32 + quad * 8);

  f32x4 acc[8] = {};                    // out^T: vcol = vc0+mt*16+quad*4+r, qrow = l16
  float m = -1e30f, l = 0.f;
  const int qrow = q0 + l16;

  const int nkt = (q0 + 16 + 31) >> 5;  // ceil((q0+16)/32)
  for (int kt = 0; kt < nkt; ++kt) {
    const int k0 = kt * 32;

    // ---- S^T (32 keys x 16 qrows) ----
    f32x4 st[2] = {};
    for (int h = 0; h < 2; ++h) {
      const __bf16* kp = k3b + (size_t)(k0 + h * 16 + l16) * DH_;
      for (int c = 0; c < 4; ++c) {
        bf16x8 kf = *(const bf16x8*)(kp + c * 32 + quad * 8);
        st[h] = __builtin_amdgcn_mfma_f32_16x16x32_bf16(kf, qf[c], st[h], 0, 0, 0);
      }
    }

    // ---- causal mask + online softmax ----
    float mloc = -1e30f;
    for (int h = 0; h < 2; ++h)
      for (int r = 0; r < 4; ++r) {
        int key = k0 + h * 16 + quad * 4 + r;
        float s = (key <= qrow) ? st[h][r] : -1e30f;
        st[h][r] = s;
        mloc = fmaxf(mloc, s);
      }
    mloc = fmaxf(mloc, __shfl_xor(mloc, 16));
    mloc = fmaxf(mloc, __shfl_xor(mloc, 32));
    float mnew = fmaxf(m, mloc);
    float alpha = __expf(m - mnew);
    float lloc = 0.f;
    bf16x4 pb[2];
    for (int h = 0; h < 2; ++h)
      for (int r = 0; r < 4; ++r) {
        float p = __expf(st[h][r] - mnew);
        lloc += p;
        pb[h][r] = (__bf16)p;
      }
    lloc += __shfl_xor(lloc, 16);
    lloc += __shfl_xor(lloc, 32);
    l = l * alpha + lloc;
    m = mnew;

    // ---- P -> LDS [qrow][key] (b64 writes: keys quad*4..+3) ----
    for (int h = 0; h < 2; ++h)
      *(bf16x4*)((char*)Pb[wave] + l16 * 80 + (h * 16 + quad * 4) * 2) = pb[h];

    // rescale accumulator (skip when no row's max moved)
    if (__any(alpha < 1.f))
      for (int mt = 0; mt < 8; ++mt) acc[mt] *= alpha;

    // ---- PV: B-frag = P[key=quad*8+j][qrow=l16] ----
    bf16x8 pf = *(bf16x8*)((char*)Pb[wave] + l16 * 80 + quad * 16);
    for (int mt = 0; mt < 8; ++mt) {
      bf16x8 vf = *(const bf16x8*)(vtb + (size_t)(mt * 16 + l16) * S_ + k0 + quad * 8);
      acc[mt] = __builtin_amdgcn_mfma_f32_16x16x32_bf16(vf, pf, acc[mt], 0, 0, 0);
    }
  }

  // ---- epilogue: out[qrow][vc0+vcol] = acc/l ----
  float inv = 1.0f / l;
  __bf16* op = attn + ((size_t)b * S_ + q0 + l16) * DV_ + vc0;
  for (int mt = 0; mt < 8; ++mt) {
    bf16x4 ob;
    for (int r = 0; r < 4; ++r) ob[r] = (__bf16)(acc[mt][r] * inv);
    *(bf16x4*)(op + mt * 16 + quad * 4) = ob;
  }
}

// ---------------------------------------------------------------------------
extern "C" void kernel_launch(void* const* d_in, const int* in_sizes, int n_in,
                              void* d_out, int out_size, void* d_ws, size_t ws_size,
                              hipStream_t stream) {
  const float* q  = (const float*)d_in[0];
  const float* k  = (const float*)d_in[1];
  const float* v  = (const float*)d_in[2];
  const float* w1 = (const float*)d_in[3];
  const float* w2 = (const float*)d_in[4];
  const float* w3 = (const float*)d_in[5];
  const float* w4 = (const float*)d_in[6];
  const float* w6 = (const float*)d_in[7];
  const float* w7 = (const float*)d_in[8];
  float* out = (float*)d_out;

  char* ws = (char*)d_ws;
  __bf16* W12T = (__bf16*)(ws + 0);          //  128x1024 bf16  256KB
  __bf16* W46T = (__bf16*)(ws + 262144);     //  128x1024 bf16  256KB
  __bf16* w3T  = (__bf16*)(ws + 524288);     //  512x1024 bf16    1MB
  __bf16* W7sT = (__bf16*)(ws + 1572864);    //  512x512  bf16  512KB
  __bf16* q2   = (__bf16*)(ws + 2097152);    // 16384x128 bf16    4MB
  __bf16* k3   = (__bf16*)(ws + 6291456);    // 16384x128 bf16    4MB
  __bf16* q3   = (__bf16*)(ws + 10485760);   // 16384x512 bf16   16MB
  __bf16* attn = (__bf16*)(ws + 27262976);   // 16384x512 bf16   16MB
  __bf16* VT   = (__bf16*)(ws + 44040192);   // 8x512x2048 bf16  16MB
  // total ws use: ~58MB

  prep_w12<<<dim3(512, 2), 256, 0, stream>>>(w1, w2, w4, w6, W12T, W46T);
  prep_w3_w7<<<dim3(3072), 256, 0, stream>>>(w3, w7, w3T, W7sT);
  prep_vt<<<dim3(64, 16, 8), 256, 0, stream>>>(v, VT);

  gemm_mfma<float, __bf16, false><<<dim3(128, 1), 256, 0, stream>>>(
      q, (const float*)nullptr, W12T, q2, 16384, 128, 1024);
  gemm_mfma<float, __bf16, false><<<dim3(128, 1), 256, 0, stream>>>(
      k, (const float*)nullptr, W46T, k3, 16384, 128, 1024);
  gemm_mfma<float, __bf16, false><<<dim3(128, 4), 256, 0, stream>>>(
      q, (const float*)nullptr, w3T, q3, 16384, 512, 1024);

  flash_attn_mfma<<<dim3(1024), 256, 0, stream>>>(q2, k3, VT, attn);

  gemm_mfma<__bf16, float, true><<<dim3(128, 4), 256, 0, stream>>>(
      attn, q3, W7sT, out, 16384, 512, 512);
}

// Round 4
// 546.277 us; speedup vs baseline: 1.3501x; 1.3501x over previous
//
#include <hip/hip_runtime.h>
#include <hip/hip_bf16.h>

// dims
#define B_ 8
#define S_ 2048
#define D_ 1024
#define H1_ 512
#define DH_ 128
#define DV_ 512
#define DOUT_ 512

typedef __bf16 bf16x8 __attribute__((ext_vector_type(8)));
typedef __bf16 bf16x4 __attribute__((ext_vector_type(4)));
typedef float  f32x4  __attribute__((ext_vector_type(4)));

#define SM_SCALE 0.08838834764831845f  // 1/sqrt(128), folded into W12T

// ---------------------------------------------------------------------------
// prep 1: W12T[h][d] = scale * sum_j w1[d][j]*w2[j][h]; W46T likewise (no scale)
// ---------------------------------------------------------------------------
__global__ __launch_bounds__(256) void prep_w12(
    const float* __restrict__ w1, const float* __restrict__ w2,
    const float* __restrict__ w4, const float* __restrict__ w6,
    __bf16* __restrict__ w12t, __bf16* __restrict__ w46t) {
  int tid = blockIdx.x * 256 + threadIdx.x;   // 131072 threads
  const float* wa; const float* wb; __bf16* o; float sc;
  if (blockIdx.y == 0) { wa = w1; wb = w2; o = w12t; sc = SM_SCALE; }
  else                 { wa = w4; wb = w6; o = w46t; sc = 1.0f; }
  int h = tid & 127;        // 0..127
  int d = tid >> 7;         // 0..1023
  float acc = 0.f;
  for (int j = 0; j < H1_; ++j)
    acc += wa[d * H1_ + j] * wb[j * DH_ + h];
  o[h * D_ + d] = (__bf16)(acc * sc);   // transposed store
}

// ---------------------------------------------------------------------------
// prep 2: w3T[n][d] = w3[d][n];  W7sT[n][k] = w7[k][n] + w7[k+512][n]
// ---------------------------------------------------------------------------
__global__ __launch_bounds__(256) void prep_w3_w7(
    const float* __restrict__ w3, const float* __restrict__ w7,
    __bf16* __restrict__ w3t, __bf16* __restrict__ w7st) {
  int tid = blockIdx.x * 256 + threadIdx.x;   // 786432 threads
  if (tid < D_ * DV_) {
    int n = tid & 511, d = tid >> 9;
    w3t[n * D_ + d] = (__bf16)w3[d * DV_ + n];
  } else {
    int t = tid - D_ * DV_;
    int n = t & 511, kk = t >> 9;
    w7st[n * DV_ + kk] = (__bf16)(w7[kk * DOUT_ + n] + w7[(kk + DV_) * DOUT_ + n]);
  }
}

// ---------------------------------------------------------------------------
// prep 3: VT[b][n][t] = (bf16) v[b][t][n]   (32x32 LDS tile transpose)
// ---------------------------------------------------------------------------
__global__ __launch_bounds__(256) void prep_vt(
    const float* __restrict__ v, __bf16* __restrict__ vt) {
  __shared__ float tile[32][33];
  int b = blockIdx.z;
  int t0 = blockIdx.x * 32, n0 = blockIdx.y * 32;
  int tx = threadIdx.x & 31, ty = threadIdx.x >> 5;  // 32x8
  const float* vb = v + (size_t)b * S_ * DV_;
  for (int i = 0; i < 4; ++i)
    tile[ty + 8 * i][tx] = vb[(size_t)(t0 + ty + 8 * i) * DV_ + n0 + tx];
  __syncthreads();
  __bf16* vtb = vt + (size_t)b * DV_ * S_;
  for (int i = 0; i < 4; ++i)
    vtb[(size_t)(n0 + ty + 8 * i) * S_ + t0 + tx] = (__bf16)tile[tx][ty + 8 * i];
}

// ---------------------------------------------------------------------------
// bf16 MFMA GEMM: C = A @ B, BT given N x K. MT = per-wave m-tile count;
// block covers (MT*32) x 128.  MT=4 -> 128 rows, MT=2 -> 64 rows (for small-N
// GEMMs so the grid still fills 256 CUs).
// ---------------------------------------------------------------------------
template <int MT, typename AT, typename OT, bool FUSE>
__global__ __launch_bounds__(256) void gemm_mfma(
    const AT* __restrict__ A1, const AT* __restrict__ A2,
    const __bf16* __restrict__ BT, OT* __restrict__ C,
    const int M, const int N, const int K) {
  __shared__ __bf16 As[(MT * 32) * 40];
  const int tid = threadIdx.x;
  const int mBase = blockIdx.x * (MT * 32);
  const int nBase = blockIdx.y * 128;
  const int wave = tid >> 6, lane = tid & 63;
  const int wr = wave >> 1, wc = wave & 1;
  const int l16 = lane & 15, quad = lane >> 4;

  f32x4 acc[MT][4] = {};
  const int nb = nBase + wc * 64;

  bf16x8 bfr[4], bnx[4];
  for (int nt = 0; nt < 4; ++nt)
    bfr[nt] = *(const bf16x8*)(BT + (size_t)(nb + nt * 16 + l16) * K + quad * 8);

  for (int k0 = 0; k0 < K; k0 += 32) {
    for (int i = 0; i < MT; ++i) {
      int ch = tid + 256 * i;
      int row = ch >> 3, k4 = (ch & 7) << 2;
      size_t off = (size_t)(mBase + row) * K + k0 + k4;
      float f0, f1, f2, f3;
      if constexpr (sizeof(AT) == 4) {
        float4 vv = *(const float4*)((const float*)A1 + off);
        f0 = vv.x; f1 = vv.y; f2 = vv.z; f3 = vv.w;
        if constexpr (FUSE) {
          float4 v2 = *(const float4*)((const float*)A2 + off);
          f0 += v2.x; f1 += v2.y; f2 += v2.z; f3 += v2.w;
        }
      } else {
        bf16x4 vv = *(const bf16x4*)((const __bf16*)A1 + off);
        f0 = (float)vv[0]; f1 = (float)vv[1]; f2 = (float)vv[2]; f3 = (float)vv[3];
        if constexpr (FUSE) {
          bf16x4 v2 = *(const bf16x4*)((const __bf16*)A2 + off);
          f0 += (float)v2[0]; f1 += (float)v2[1]; f2 += (float)v2[2]; f3 += (float)v2[3];
        }
      }
      bf16x4 w; w[0] = (__bf16)f0; w[1] = (__bf16)f1; w[2] = (__bf16)f2; w[3] = (__bf16)f3;
      *(bf16x4*)&As[row * 40 + k4] = w;
    }
    __syncthreads();

    if (k0 + 32 < K)
      for (int nt = 0; nt < 4; ++nt)
        bnx[nt] = *(const bf16x8*)(BT + (size_t)(nb + nt * 16 + l16) * K + (k0 + 32) + quad * 8);

    bf16x8 afr[MT];
    for (int mt = 0; mt < MT; ++mt)
      afr[mt] = *(bf16x8*)&As[(wr * (MT * 16) + mt * 16 + l16) * 40 + quad * 8];

    for (int mt = 0; mt < MT; ++mt)
      for (int nt = 0; nt < 4; ++nt)
        acc[mt][nt] = __builtin_amdgcn_mfma_f32_16x16x32_bf16(afr[mt], bfr[nt], acc[mt][nt], 0, 0, 0);
    __syncthreads();

    for (int nt = 0; nt < 4; ++nt) bfr[nt] = bnx[nt];
  }

  for (int mt = 0; mt < MT; ++mt) {
    int rowb = mBase + wr * (MT * 16) + mt * 16 + quad * 4;
    for (int nt = 0; nt < 4; ++nt) {
      int col = nBase + wc * 64 + nt * 16 + l16;
      for (int r = 0; r < 4; ++r)
        C[(size_t)(rowb + r) * N + col] = (OT)acc[mt][nt][r];
    }
  }
}

// ---------------------------------------------------------------------------
// MFMA flash attention, MLP-oriented restructure.
// 256 blocks (1/CU), 4 waves: wave = (qsub, vhalf); TQ=32, TK=32.
// Each block runs TWO q-tiles: j = s and j = 63-s  -> exactly 65 iters/block
// (perfect balance). Per iter:
//   - write prefetched K regs -> double-buffered LDS, one __syncthreads
//   - prefetch next K tile (consumed next iter), batch-load 16 vf frags
//     (consumed after softmax) => deep MLP, latency hidden
//   - S^T = K3 @ Q2^T from LDS (8 MFMA), online softmax (alpha lane-uniform),
//     P via per-wave LDS, PV = VT @ P (16 MFMA, vf from regs)
// ---------------------------------------------------------------------------
__global__ __launch_bounds__(256, 1) void flash_attn_mfma(
    const __bf16* __restrict__ q2, const __bf16* __restrict__ k3,
    const __bf16* __restrict__ vt, __bf16* __restrict__ attn) {
  __shared__ __bf16 Kb[2][32 * 132];   // K tile 32x128, row stride 264B
  __shared__ __bf16 Pb[4][16 * 40];    // per-wave P, row stride 80B
  const int tid = threadIdx.x;
  const int wave = tid >> 6, lane = tid & 63;
  const int l16 = lane & 15, quad = lane >> 4;
  const int qsub = wave & 1, vhalf = wave >> 1;
  const int b = blockIdx.x & 7;        // batch -> XCD round robin
  const int s = blockIdx.x >> 3;       // 0..31

  const __bf16* k3b = k3 + (size_t)b * S_ * DH_;
  const __bf16* vtb = vt + ((size_t)b * DV_ + vhalf * 256) * S_;
  // K staging: thread covers chunks tid and tid+256 (rows krow0, krow0+16)
  const int krow0 = tid >> 4;          // 0..15
  const int koff  = tid & 15;          // 16B chunk within row

  for (int pass = 0; pass < 2; ++pass) {
    const int j = pass ? (63 - s) : s;
    const int q0 = j * 32;
    const int nkt = j + 1;
    const int qrow = q0 + qsub * 16 + l16;

    // Q B-frags for this pass
    const __bf16* q2b = q2 + ((size_t)b * S_ + q0 + qsub * 16) * DH_;
    bf16x8 qf[4];
    for (int c = 0; c < 4; ++c)
      qf[c] = *(const bf16x8*)(q2b + (size_t)l16 * DH_ + c * 32 + quad * 8);

    f32x4 acc[16] = {};
    float m = -1e30f, l = 0.f;

    // prologue: K tile 0 into regs
    bf16x8 kreg0 = *(const bf16x8*)(k3b + (size_t)(krow0) * DH_ + koff * 8);
    bf16x8 kreg1 = *(const bf16x8*)(k3b + (size_t)(16 + krow0) * DH_ + koff * 8);

    __syncthreads();   // protect Kb against previous pass's trailing readers

    for (int kt = 0; kt < nkt; ++kt) {
      const int k0 = kt * 32;
      __bf16* kb = Kb[kt & 1];
      // ---- write prefetched K tile to LDS ----
      *(bf16x8*)((char*)kb + krow0 * 264 + koff * 16) = kreg0;
      *(bf16x8*)((char*)kb + (16 + krow0) * 264 + koff * 16) = kreg1;
      __syncthreads();

      // ---- prefetch next K tile (consumed next iter) ----
      if (kt + 1 < nkt) {
        kreg0 = *(const bf16x8*)(k3b + (size_t)(k0 + 32 + krow0) * DH_ + koff * 8);
        kreg1 = *(const bf16x8*)(k3b + (size_t)(k0 + 48 + krow0) * DH_ + koff * 8);
      }
      // ---- batch-load V frags (consumed at PV, ~500 cyc later) ----
      bf16x8 vf[16];
      for (int mt = 0; mt < 16; ++mt)
        vf[mt] = *(const bf16x8*)(vtb + (size_t)(mt * 16 + l16) * S_ + k0 + quad * 8);

      // ---- S^T (32 keys x 16 qrows) from LDS ----
      f32x4 st[2] = {};
      const char* kbase = (const char*)kb + l16 * 264 + quad * 16;
      for (int h = 0; h < 2; ++h)
        for (int c = 0; c < 4; ++c) {
          bf16x8 kf = *(const bf16x8*)(kbase + h * 16 * 264 + c * 64);
          st[h] = __builtin_amdgcn_mfma_f32_16x16x32_bf16(kf, qf[c], st[h], 0, 0, 0);
        }

      // ---- causal mask + online softmax ----
      float mloc = -1e30f;
      for (int h = 0; h < 2; ++h)
        for (int r = 0; r < 4; ++r) {
          int key = k0 + h * 16 + quad * 4 + r;
          float sv = (key <= qrow) ? st[h][r] : -1e30f;
          st[h][r] = sv;
          mloc = fmaxf(mloc, sv);
        }
      mloc = fmaxf(mloc, __shfl_xor(mloc, 16));
      mloc = fmaxf(mloc, __shfl_xor(mloc, 32));
      float mnew = fmaxf(m, mloc);
      float alpha = __expf(m - mnew);
      float lloc = 0.f;
      bf16x4 pb[2];
      for (int h = 0; h < 2; ++h)
        for (int r = 0; r < 4; ++r) {
          float p = __expf(st[h][r] - mnew);
          lloc += p;
          pb[h][r] = (__bf16)p;
        }
      lloc += __shfl_xor(lloc, 16);
      lloc += __shfl_xor(lloc, 32);
      l = l * alpha + lloc;
      m = mnew;

      // ---- P -> per-wave LDS [qrow][key] ----
      for (int h = 0; h < 2; ++h)
        *(bf16x4*)((char*)Pb[wave] + l16 * 80 + (h * 16 + quad * 4) * 2) = pb[h];

      if (__any(alpha < 1.f))
        for (int mt = 0; mt < 16; ++mt) acc[mt] *= alpha;

      // ---- PV: B-frag = P[key=quad*8+j][qrow=l16], A-frags from vf regs ----
      bf16x8 pf = *(bf16x8*)((char*)Pb[wave] + l16 * 80 + quad * 16);
      for (int mt = 0; mt < 16; ++mt)
        acc[mt] = __builtin_amdgcn_mfma_f32_16x16x32_bf16(vf[mt], pf, acc[mt], 0, 0, 0);
    }

    // ---- epilogue: out[qrow][vhalf*256 + vcol] = acc/l ----
    float inv = 1.0f / l;
    __bf16* op = attn + ((size_t)b * S_ + qrow) * DV_ + vhalf * 256;
    for (int mt = 0; mt < 16; ++mt) {
      bf16x4 ob;
      for (int r = 0; r < 4; ++r) ob[r] = (__bf16)(acc[mt][r] * inv);
      *(bf16x4*)(op + mt * 16 + quad * 4) = ob;
    }
  }
}

// ---------------------------------------------------------------------------
extern "C" void kernel_launch(void* const* d_in, const int* in_sizes, int n_in,
                              void* d_out, int out_size, void* d_ws, size_t ws_size,
                              hipStream_t stream) {
  const float* q  = (const float*)d_in[0];
  const float* k  = (const float*)d_in[1];
  const float* v  = (const float*)d_in[2];
  const float* w1 = (const float*)d_in[3];
  const float* w2 = (const float*)d_in[4];
  const float* w3 = (const float*)d_in[5];
  const float* w4 = (const float*)d_in[6];
  const float* w6 = (const float*)d_in[7];
  const float* w7 = (const float*)d_in[8];
  float* out = (float*)d_out;

  char* ws = (char*)d_ws;
  __bf16* W12T = (__bf16*)(ws + 0);          //  128x1024 bf16  256KB
  __bf16* W46T = (__bf16*)(ws + 262144);     //  128x1024 bf16  256KB
  __bf16* w3T  = (__bf16*)(ws + 524288);     //  512x1024 bf16    1MB
  __bf16* W7sT = (__bf16*)(ws + 1572864);    //  512x512  bf16  512KB
  __bf16* q2   = (__bf16*)(ws + 2097152);    // 16384x128 bf16    4MB
  __bf16* k3   = (__bf16*)(ws + 6291456);    // 16384x128 bf16    4MB
  __bf16* q3   = (__bf16*)(ws + 10485760);   // 16384x512 bf16   16MB
  __bf16* attn = (__bf16*)(ws + 27262976);   // 16384x512 bf16   16MB
  __bf16* VT   = (__bf16*)(ws + 44040192);   // 8x512x2048 bf16  16MB
  // total ws use: ~58MB

  prep_w12<<<dim3(512, 2), 256, 0, stream>>>(w1, w2, w4, w6, W12T, W46T);
  prep_w3_w7<<<dim3(3072), 256, 0, stream>>>(w3, w7, w3T, W7sT);
  prep_vt<<<dim3(64, 16, 8), 256, 0, stream>>>(v, VT);

  // q2 = q @ W12   (M=16384, N=128, K=1024)  -- 64-row blocks: 256 blocks
  gemm_mfma<2, float, __bf16, false><<<dim3(256, 1), 256, 0, stream>>>(
      q, (const float*)nullptr, W12T, q2, 16384, 128, 1024);
  // k3 = k @ W46
  gemm_mfma<2, float, __bf16, false><<<dim3(256, 1), 256, 0, stream>>>(
      k, (const float*)nullptr, W46T, k3, 16384, 128, 1024);
  // q3 = q @ w3    (N=512, K=1024)
  gemm_mfma<4, float, __bf16, false><<<dim3(128, 4), 256, 0, stream>>>(
      q, (const float*)nullptr, w3T, q3, 16384, 512, 1024);

  // causal attention
  flash_attn_mfma<<<dim3(256), 256, 0, stream>>>(q2, k3, VT, attn);

  // out = (attn + q3) @ W7s   (N=512, K=512), fp32 output
  gemm_mfma<4, __bf16, float, true><<<dim3(128, 4), 256, 0, stream>>>(
      attn, q3, W7sT, out, 16384, 512, 512);
}